// Round 10
// baseline (223.983 us; speedup 1.0000x reference)
//
#include <hip/hip_runtime.h>
#include <math.h>

#define T_TOK 65536
#define K_CODE 1024
#define E_DIM 64
#define DECAYF 0.99f
#define EPSF 1e-5f

// ---- dist_kernel geometry ----
#define TT 256            // tokens per block (8 waves x 32 rows)
#define QCAP 4096         // candidate queue capacity (expected ~1300)
// acc-domain margin (r4/r5/r7-harness-verified filter): dist = xn - 2*acc + wn,
// dist-window = 2*HACC. Rigorous need: acc-margin >= (2*bf16_err + wn_max)/2
// ~= 5.2e-4. HACC = 1.3e-3 gives ~2.5x slack. The ONLINE threshold
// thr = runningmax - HACC <= finalmax - HACC only ENLARGES the candidate
// set vs the verified two-pass filter (superset preserved at every tile).
#define HACC 1.3e-3f

typedef short short8 __attribute__((ext_vector_type(8)));
typedef float f32x16 __attribute__((ext_vector_type(16)));

// --- exact-rounding helpers: block ffp-contract=fast fusion ---
__device__ __forceinline__ float mul_nf(float a, float b) {
#pragma clang fp contract(off)
    return a * b;
}
__device__ __forceinline__ float add_nf(float a, float b) {
#pragma clang fp contract(off)
    return a + b;
}
__device__ __forceinline__ float sub_nf(float a, float b) {
#pragma clang fp contract(off)
    return a - b;
}

// numpy pairwise ||x||^2 from a global row pointer (float4 loads)
__device__ __forceinline__ float np_sq_row(const float* xrow) {
    const float4* xp = reinterpret_cast<const float4*>(xrow);
    float r[8];
#pragma unroll
    for (int g = 0; g < 8; ++g) {
        float4 va = xp[2 * g], vb = xp[2 * g + 1];
        float e[8] = {va.x, va.y, va.z, va.w, vb.x, vb.y, vb.z, vb.w};
#pragma unroll
        for (int j = 0; j < 8; ++j) {
            if (g == 0) r[j] = mul_nf(e[j], e[j]);
            else        r[j] = add_nf(r[j], mul_nf(e[j], e[j]));
        }
    }
    float s01 = add_nf(r[0], r[1]);
    float s23 = add_nf(r[2], r[3]);
    float s45 = add_nf(r[4], r[5]);
    float s67 = add_nf(r[6], r[7]);
    return add_nf(add_nf(s01, s23), add_nf(s45, s67));
}

__device__ __forceinline__ unsigned f2bf_rne(float f) {
    unsigned u = __float_as_uint(f);
    u += 0x7FFFu + ((u >> 16) & 1u);
    return (u >> 16);
}

// exact fp32 recheck: bit-identical arithmetic to the verified argmin chain
// (ascending i single-accumulator FMA, dist = fl(fl(xn - fl(d+d)) + wn)),
// first-min semantics via u64 (monotone_dist<<32 | code) atomicMin on LDS.
__device__ __forceinline__ void exact_key(int t0, int tl, int code, float wn,
                                          const float* __restrict__ z_e,
                                          const float* __restrict__ embed,
                                          const float* xn_s,
                                          unsigned long long* key_s) {
    const float4* xp = reinterpret_cast<const float4*>(z_e + (size_t)(t0 + tl) * E_DIM);
    const float4* wp = reinterpret_cast<const float4*>(embed + (size_t)code * E_DIM);
    float d = 0.f;
#pragma unroll
    for (int m = 0; m < 16; ++m) {
        float4 x4 = xp[m];
        float4 w4 = wp[m];
        d = __builtin_fmaf(x4.x, w4.x, d);
        d = __builtin_fmaf(x4.y, w4.y, d);
        d = __builtin_fmaf(x4.z, w4.z, d);
        d = __builtin_fmaf(x4.w, w4.w, d);
    }
    float dist = add_nf(sub_nf(xn_s[tl], d + d), wn);
    unsigned b = __float_as_uint(dist);
    unsigned mk = (b & 0x80000000u) ? ~b : (b | 0x80000000u);
    atomicMin(key_s + tl, ((unsigned long long)mk << 32) | (unsigned)code);
}

// ws layout (floats):
// [0]                  diff accumulator
// [1, 16)              pad
// [16, 16+8192)        onehot replicas (8*1024)
// [8208, +nrep*65536)  embed_sum replicas
// single contiguous memset (async dispatch — r9 showed fused zeroing
// regresses the dist prologue): [0, 8208 + nrep*65536)

// MFMA approx-filter + exact-recheck argmin, fully fused, SINGLE MFMA sweep.
// Block = 512 thr = 8 waves; 256 tokens; 256 blocks (token-exclusive -> the
// r3-verified in-block epilogue applies; no combine kernel, no global keys).
// Full 128 KB bf16 codebook staged ONCE (swizzled; thread converts rows tid
// and tid+512, computing np-exact wnorm — r3-verified staging).
// ONLINE filter (replaces the verified two-pass): per-(lane,reg) running max
// maxr; every 4th tile cross-lane-reduce it and refresh thr = maxr - HACC;
// enqueue any acc >= thr immediately. thr <= finalmax - HACC at all times,
// so the candidate set is a SUPERSET of the verified two-pass set (the true
// winner's margin proof is unchanged); drain + exact chain unchanged.
__global__ __launch_bounds__(512) void dist_kernel(const float* __restrict__ z_e,
                                                   const float* __restrict__ embed,
                                                   float* __restrict__ out_zq,
                                                   float* __restrict__ out_ind,
                                                   float* __restrict__ diff_acc,
                                                   float* __restrict__ esum_rep,
                                                   float* __restrict__ onehot_rep,
                                                   int rep_mask) {
    __shared__ unsigned short Ws[K_CODE * E_DIM];  // 128 KB, swizzled slots
    __shared__ float wn_s[K_CODE];                 // 4 KB
    __shared__ float xn_s[TT];                     // 1 KB
    __shared__ unsigned long long key_s[TT];       // 2 KB
    __shared__ unsigned q_s[QCAP];                 // 16 KB
    __shared__ int bi_s[TT];                       // 1 KB
    __shared__ int qc_s;

    int tid = threadIdx.x;
    int lane = tid & 63;
    int wave = tid >> 6;
    int g = lane >> 5;  // k-group within MFMA operand
    int t0 = blockIdx.x * TT;

    if (tid == 0) qc_s = 0;
    if (tid < TT) {
        key_s[tid] = ~0ull;
        // ||x||^2 per token (exact numpy pairwise)
        xn_s[tid] = np_sq_row(z_e + (size_t)(t0 + tid) * E_DIM);
    }

    // --- fused codebook convert + stage + wnorm: thread owns rows tid, tid+512 ---
#pragma unroll
    for (int rr = 0; rr < 2; ++rr) {
        int row = tid + rr * 512;
        const float4* wp = reinterpret_cast<const float4*>(embed + (size_t)row * E_DIM);
        uint4* WsQ = reinterpret_cast<uint4*>(Ws);
        float r8[8];
#pragma unroll
        for (int gq = 0; gq < 8; ++gq) {
            float4 va = wp[2 * gq], vb = wp[2 * gq + 1];
            float e[8] = {va.x, va.y, va.z, va.w, vb.x, vb.y, vb.z, vb.w};
#pragma unroll
            for (int j = 0; j < 8; ++j) {
                if (gq == 0) r8[j] = mul_nf(e[j], e[j]);
                else         r8[j] = add_nf(r8[j], mul_nf(e[j], e[j]));
            }
            unsigned p0 = f2bf_rne(e[0]) | (f2bf_rne(e[1]) << 16);
            unsigned p1 = f2bf_rne(e[2]) | (f2bf_rne(e[3]) << 16);
            unsigned p2 = f2bf_rne(e[4]) | (f2bf_rne(e[5]) << 16);
            unsigned p3 = f2bf_rne(e[6]) | (f2bf_rne(e[7]) << 16);
            // logical slot gq (elems 8gq..8gq+7) at phys slot gq ^ (row&7)
            WsQ[row * 8 + (gq ^ (row & 7))] = make_uint4(p0, p1, p2, p3);
        }
        float s01 = add_nf(r8[0], r8[1]);
        float s23 = add_nf(r8[2], r8[3]);
        float s45 = add_nf(r8[4], r8[5]);
        float s67 = add_nf(r8[6], r8[7]);
        wn_s[row] = add_nf(add_nf(s01, s23), add_nf(s45, s67));  // np-exact
    }

    // a-frags: lane supplies A[m = lane&31][k = 16*kc + 8*g + j], bf16.
    int arow = wave * 32 + (lane & 31);
    const float* xrow = z_e + (size_t)(t0 + arow) * E_DIM;
    short8 afr[4];
#pragma unroll
    for (int kc = 0; kc < 4; ++kc) {
        int base = kc * 16 + g * 8;
        float4 a = *reinterpret_cast<const float4*>(xrow + base);
        float4 b = *reinterpret_cast<const float4*>(xrow + base + 4);
        afr[kc][0] = (short)f2bf_rne(a.x);
        afr[kc][1] = (short)f2bf_rne(a.y);
        afr[kc][2] = (short)f2bf_rne(a.z);
        afr[kc][3] = (short)f2bf_rne(a.w);
        afr[kc][4] = (short)f2bf_rne(b.x);
        afr[kc][5] = (short)f2bf_rne(b.y);
        afr[kc][6] = (short)f2bf_rne(b.z);
        afr[kc][7] = (short)f2bf_rne(b.w);
    }

    __syncthreads();  // Ws, wn_s, xn_s, key_s ready

    // ---- SINGLE sweep: MFMA + running max + online enqueue ----
    float maxr[16], thr[16];
#pragma unroll
    for (int r = 0; r < 16; ++r) maxr[r] = -INFINITY;

#pragma unroll 4
    for (int tile = 0; tile < 32; ++tile) {
        int code = tile * 32 + (lane & 31);
        f32x16 acc;
#pragma unroll
        for (int i = 0; i < 16; ++i) acc[i] = 0.f;
#pragma unroll
        for (int kc = 0; kc < 4; ++kc) {
            int ps = (2 * kc + g) ^ (code & 7);
            short8 bfr = *reinterpret_cast<const short8*>(&Ws[code * E_DIM + ps * 8]);
            acc = __builtin_amdgcn_mfma_f32_32x32x16_bf16(afr[kc], bfr, acc, 0, 0, 0);
        }
        // running per-(lane,reg) max, including this tile
#pragma unroll
        for (int r = 0; r < 16; ++r) maxr[r] = fmaxf(maxr[r], acc[r]);
        // every 4th tile (incl. tile 0): cross-lane fold -> fresh threshold.
        // xor masks < 32 stay inside the lane>>5 row-group (verified reduce).
        if ((tile & 3) == 0) {
#pragma unroll
            for (int off = 1; off < 32; off <<= 1) {
#pragma unroll
                for (int r = 0; r < 16; ++r)
                    maxr[r] = fmaxf(maxr[r], __shfl_xor(maxr[r], off, 64));
            }
#pragma unroll
            for (int r = 0; r < 16; ++r) thr[r] = maxr[r] - HACC;
        }
        // online enqueue: acc >= thr (thr <= finalmax - HACC -> superset)
        float tmax = -INFINITY;
#pragma unroll
        for (int r = 0; r < 16; ++r) tmax = fmaxf(tmax, acc[r] - thr[r]);
        if (tmax >= 0.f) {  // uncommon
#pragma unroll
            for (int r = 0; r < 16; ++r) {
                if (acc[r] >= thr[r]) {
                    int row = (r & 3) + 8 * (r >> 2) + 4 * g;
                    int tl = wave * 32 + row;
                    int slot = atomicAdd(&qc_s, 1);
                    if (slot < QCAP)
                        q_s[slot] = ((unsigned)tl << 10) | (unsigned)code;
                    else  // overflow fallback: exact inline (correct, rare)
                        exact_key(t0, tl, code, wn_s[code], z_e, embed, xn_s, key_s);
                }
            }
        }
    }
    __syncthreads();

    // drain candidate queue with the exact fp32 chain
    int qn = qc_s;
    if (qn > QCAP) qn = QCAP;
    for (int e = tid; e < qn; e += 512) {
        unsigned q = q_s[e];
        int tl = (int)(q >> 10);
        int code = (int)(q & 1023u);
        exact_key(t0, tl, code, wn_s[code], z_e, embed, xn_s, key_s);
    }
    __syncthreads();

    // ---- fused epilogue (r3/r7-verified): ind, z_q, diff, EMA scatter ----
    if (tid < TT) {
        int bi = (int)(unsigned)(key_s[tid] & 1023ull);
        bi_s[tid] = bi;
        out_ind[t0 + tid] = (float)bi;
    }
    __syncthreads();

    int rep = blockIdx.x & rep_mask;
    float* esum = esum_rep + (size_t)rep * (K_CODE * E_DIM);
    float* onehot = onehot_rep + (size_t)rep * K_CODE;

    float ds = 0.f;
#pragma unroll 4
    for (int it = 0; it < 32; ++it) {
        int tl = wave * 32 + it;                  // wave-uniform
        int bi = bi_s[tl];                        // broadcast
        float xv = z_e[(size_t)(t0 + tl) * E_DIM + lane];   // coalesced row
        float wv = embed[(size_t)bi * E_DIM + lane];        // coalesced row
        float rr = sub_nf(wv, xv);                          // np: r = fl(w-x)
        out_zq[(size_t)(t0 + tl) * E_DIM + lane] = add_nf(xv, rr);  // fl(x+r)
        ds = __builtin_fmaf(rr, rr, ds);
        atomicAdd(&esum[(size_t)bi * E_DIM + lane], xv);
        if (lane == 0) atomicAdd(&onehot[bi], 1.0f);
    }
#pragma unroll
    for (int o = 32; o > 0; o >>= 1) ds += __shfl_down(ds, o, 64);
    if (lane == 0) atomicAdd(diff_acc, ds);
}

// Fused finalize (r5/r6/r7/r9 harness-verified): every block redundantly
// computes ncs[1024] + n with the same reduction tree as the verified
// finalize_cs; block 0 writes out_ncs/out_diff; each block updates its 16
// embed rows (identical mapping/arithmetic to the verified finalize_embed).
__global__ __launch_bounds__(256) void finalize_kernel(const float* __restrict__ cluster_size,
                                                       const float* __restrict__ onehot_rep,
                                                       const float* __restrict__ ws_diff,
                                                       const float* __restrict__ embed_avg,
                                                       const float* __restrict__ esum_rep,
                                                       float* __restrict__ out_diff,
                                                       float* __restrict__ out_ncs,
                                                       float* __restrict__ out_ne,
                                                       float* __restrict__ out_nea,
                                                       int nrep) {
    __shared__ float ncs_s[K_CODE];
    __shared__ float red[K_CODE];
    int tid = threadIdx.x;

#pragma unroll
    for (int i = 0; i < 4; ++i) {
        int k = tid + 256 * i;
        float oh = 0.f;
        for (int r = 0; r < nrep; ++r) oh += onehot_rep[(size_t)r * K_CODE + k];
        float ncs = DECAYF * cluster_size[k] + (1.0f - DECAYF) * oh;
        ncs_s[k] = ncs;
        red[k] = ncs;
    }
    __syncthreads();
    for (int s = 512; s > 0; s >>= 1) {
        for (int idx = tid; idx < s; idx += 256) red[idx] += red[idx + s];
        __syncthreads();
    }
    float n = red[0];

    if (blockIdx.x == 0) {
#pragma unroll
        for (int i = 0; i < 4; ++i) {
            int k = tid + 256 * i;
            out_ncs[k] = ncs_s[k];
        }
        if (tid == 0) out_diff[0] = ws_diff[0] * (1.0f / 4194304.0f);  // /2^22 exact
    }

    int k = blockIdx.x * 16 + (tid >> 4);  // row (same mapping as verified)
    int c = tid & 15;                      // float4 chunk
    float ncs = ncs_s[k];
    float cs = (ncs + EPSF) / (n + (float)K_CODE * EPSF) * n;

    size_t off = (size_t)k * E_DIM + (size_t)c * 4;
    float4 s4 = make_float4(0.f, 0.f, 0.f, 0.f);
    for (int r = 0; r < nrep; ++r) {
        float4 v = *reinterpret_cast<const float4*>(esum_rep + (size_t)r * (K_CODE * E_DIM) + off);
        s4.x += v.x; s4.y += v.y; s4.z += v.z; s4.w += v.w;
    }
    float4 a = *reinterpret_cast<const float4*>(embed_avg + off);
    float4 nea, ne;
    nea.x = DECAYF * a.x + (1.0f - DECAYF) * s4.x;
    nea.y = DECAYF * a.y + (1.0f - DECAYF) * s4.y;
    nea.z = DECAYF * a.z + (1.0f - DECAYF) * s4.z;
    nea.w = DECAYF * a.w + (1.0f - DECAYF) * s4.w;
    ne.x = nea.x / cs; ne.y = nea.y / cs; ne.z = nea.z / cs; ne.w = nea.w / cs;
    *reinterpret_cast<float4*>(out_nea + off) = nea;
    *reinterpret_cast<float4*>(out_ne + off) = ne;
}

extern "C" void kernel_launch(void* const* d_in, const int* in_sizes, int n_in,
                              void* d_out, int out_size, void* d_ws, size_t ws_size,
                              hipStream_t stream) {
    const float* z_e = (const float*)d_in[0];
    const float* embed = (const float*)d_in[1];
    const float* cluster_size = (const float*)d_in[2];
    const float* embed_avg = (const float*)d_in[3];

    float* out = (float*)d_out;
    float* o_zq = out;                   // 4194304
    float* o_diff = out + 4194304;       // 1
    float* o_ind = out + 4194305;        // 65536
    float* o_ne = out + 4194305 + 65536; // 65536
    float* o_ncs = o_ne + 65536;         // 1024
    float* o_nea = o_ncs + 1024;         // 65536

    float* ws = (float*)d_ws;
    float* ws_diff = ws + 0;
    float* ws_onehot = ws + 16;          // 8*1024

    int nrep = 1;
    while (nrep < 8 &&
           (size_t)(8208 + (size_t)(2 * nrep) * 65536) * sizeof(float) <= ws_size)
        nrep *= 2;

    float* ws_esum = ws + 8208;          // nrep*65536

    // one contiguous clear: diff, pad, onehot, esum
    hipMemsetAsync(ws, 0, (size_t)(8208 + (size_t)nrep * 65536) * sizeof(float), stream);

    dist_kernel<<<T_TOK / TT, 512, 0, stream>>>(z_e, embed, o_zq, o_ind, ws_diff,
                                                ws_esum, ws_onehot, nrep - 1);
    finalize_kernel<<<64, 256, 0, stream>>>(cluster_size, ws_onehot, ws_diff, embed_avg,
                                            ws_esum, o_diff, o_ncs, o_ne, o_nea, nrep);
}

// Round 11
// 184.196 us; speedup vs baseline: 1.2160x; 1.2160x over previous
//
#include <hip/hip_runtime.h>
#include <math.h>

#define T_TOK 65536
#define K_CODE 1024
#define E_DIM 64
#define DECAYF 0.99f
#define EPSF 1e-5f

// ---- dist_kernel geometry ----
#define TT 256            // tokens per block (8 waves x 32 rows)
#define QCAP 2048         // candidate queue capacity (expected ~650)
// acc-domain margin (r4/r5/r7-harness-verified filter): dist = xn - 2*acc + wn,
// dist-window = 2*HACC. Rigorous need: acc-margin >= (2*bf16_err + wn_max)/2
// ~= 5.2e-4. HACC = 1.3e-3 gives ~2.5x slack.
#define HACC 1.3e-3f

typedef short short8 __attribute__((ext_vector_type(8)));
typedef float f32x16 __attribute__((ext_vector_type(16)));

// --- exact-rounding helpers: block ffp-contract=fast fusion ---
__device__ __forceinline__ float mul_nf(float a, float b) {
#pragma clang fp contract(off)
    return a * b;
}
__device__ __forceinline__ float add_nf(float a, float b) {
#pragma clang fp contract(off)
    return a + b;
}
__device__ __forceinline__ float sub_nf(float a, float b) {
#pragma clang fp contract(off)
    return a - b;
}

// numpy pairwise ||x||^2 from a global row pointer (float4 loads)
__device__ __forceinline__ float np_sq_row(const float* xrow) {
    const float4* xp = reinterpret_cast<const float4*>(xrow);
    float r[8];
#pragma unroll
    for (int g = 0; g < 8; ++g) {
        float4 va = xp[2 * g], vb = xp[2 * g + 1];
        float e[8] = {va.x, va.y, va.z, va.w, vb.x, vb.y, vb.z, vb.w};
#pragma unroll
        for (int j = 0; j < 8; ++j) {
            if (g == 0) r[j] = mul_nf(e[j], e[j]);
            else        r[j] = add_nf(r[j], mul_nf(e[j], e[j]));
        }
    }
    float s01 = add_nf(r[0], r[1]);
    float s23 = add_nf(r[2], r[3]);
    float s45 = add_nf(r[4], r[5]);
    float s67 = add_nf(r[6], r[7]);
    return add_nf(add_nf(s01, s23), add_nf(s45, s67));
}

__device__ __forceinline__ unsigned f2bf_rne(float f) {
    unsigned u = __float_as_uint(f);
    u += 0x7FFFu + ((u >> 16) & 1u);
    return (u >> 16);
}

// exact fp32 recheck: bit-identical arithmetic to the verified argmin chain
// (ascending i single-accumulator FMA, dist = fl(fl(xn - fl(d+d)) + wn)),
// first-min semantics via u64 (monotone_dist<<32 | code) atomicMin on LDS.
__device__ __forceinline__ void exact_key(int t0, int tl, int code, float wn,
                                          const float* __restrict__ z_e,
                                          const float* __restrict__ embed,
                                          const float* xn_s,
                                          unsigned long long* key_s) {
    const float4* xp = reinterpret_cast<const float4*>(z_e + (size_t)(t0 + tl) * E_DIM);
    const float4* wp = reinterpret_cast<const float4*>(embed + (size_t)code * E_DIM);
    float d = 0.f;
#pragma unroll
    for (int m = 0; m < 16; ++m) {
        float4 x4 = xp[m];
        float4 w4 = wp[m];
        d = __builtin_fmaf(x4.x, w4.x, d);
        d = __builtin_fmaf(x4.y, w4.y, d);
        d = __builtin_fmaf(x4.z, w4.z, d);
        d = __builtin_fmaf(x4.w, w4.w, d);
    }
    float dist = add_nf(sub_nf(xn_s[tl], d + d), wn);
    unsigned b = __float_as_uint(dist);
    unsigned mk = (b & 0x80000000u) ? ~b : (b | 0x80000000u);
    atomicMin(key_s + tl, ((unsigned long long)mk << 32) | (unsigned)code);
}

// ws layout (floats):
// [0]                  diff accumulator
// [1, 16)              pad
// [16, 16+8192)        onehot replicas (8*1024)
// [8208, +nrep*65536)  embed_sum replicas
// single contiguous memset (async dispatch): [0, 8208 + nrep*65536)

// MFMA approx-filter + exact-recheck argmin, fully fused (r3-verified
// structure) with QUAD-INTERLEAVED MFMA sweeps. Block = 512 thr = 8 waves;
// 256 tokens; 256 blocks (token-exclusive -> in-block epilogue, no combine).
// Full 128 KB bf16 codebook staged ONCE (r10-verified staging: thread
// converts rows tid, tid+512, computing np-exact wnorm).
// ILP fix for the 2-waves/SIMD stall: each quad processes 4 tiles with 4
// INDEPENDENT accumulator chains, MFMAs issued round-robin (t0,t1,t2,t3 per
// k-slice) so each chain's dependent MFMA arrives 4 issues later — hiding
// MFMA latency that the serial per-tile chain exposed (r3: ~75% stall).
// Tiles in a quad differ by code-stride 32, so the swizzle slot ps is
// IDENTICAL across the quad (code&7 depends only on lane) — one base addr.
// Filter semantics bit-identical to r3/r7 verified two-pass: pass 1 raw-acc
// max, fold thr = max - HACC in place, pass 2 enqueue, exact drain.
__global__ __launch_bounds__(512) void dist_kernel(const float* __restrict__ z_e,
                                                   const float* __restrict__ embed,
                                                   float* __restrict__ out_zq,
                                                   float* __restrict__ out_ind,
                                                   float* __restrict__ diff_acc,
                                                   float* __restrict__ esum_rep,
                                                   float* __restrict__ onehot_rep,
                                                   int rep_mask) {
    __shared__ unsigned short Ws[K_CODE * E_DIM];  // 128 KB, swizzled slots
    __shared__ float wn_s[K_CODE];                 // 4 KB
    __shared__ float xn_s[TT];                     // 1 KB
    __shared__ unsigned long long key_s[TT];       // 2 KB
    __shared__ unsigned q_s[QCAP];                 // 8 KB
    __shared__ int bi_s[TT];                       // 1 KB
    __shared__ int qc_s;

    int tid = threadIdx.x;
    int lane = tid & 63;
    int wave = tid >> 6;
    int g = lane >> 5;  // k-group within MFMA operand
    int t0 = blockIdx.x * TT;

    if (tid == 0) qc_s = 0;
    if (tid < TT) {
        key_s[tid] = ~0ull;
        // ||x||^2 per token (exact numpy pairwise)
        xn_s[tid] = np_sq_row(z_e + (size_t)(t0 + tid) * E_DIM);
    }

    // --- fused codebook convert + stage + wnorm (r10-verified): rows tid, tid+512 ---
#pragma unroll
    for (int rr = 0; rr < 2; ++rr) {
        int row = tid + rr * 512;
        const float4* wp = reinterpret_cast<const float4*>(embed + (size_t)row * E_DIM);
        uint4* WsQ = reinterpret_cast<uint4*>(Ws);
        float r8[8];
#pragma unroll
        for (int gq = 0; gq < 8; ++gq) {
            float4 va = wp[2 * gq], vb = wp[2 * gq + 1];
            float e[8] = {va.x, va.y, va.z, va.w, vb.x, vb.y, vb.z, vb.w};
#pragma unroll
            for (int j = 0; j < 8; ++j) {
                if (gq == 0) r8[j] = mul_nf(e[j], e[j]);
                else         r8[j] = add_nf(r8[j], mul_nf(e[j], e[j]));
            }
            unsigned p0 = f2bf_rne(e[0]) | (f2bf_rne(e[1]) << 16);
            unsigned p1 = f2bf_rne(e[2]) | (f2bf_rne(e[3]) << 16);
            unsigned p2 = f2bf_rne(e[4]) | (f2bf_rne(e[5]) << 16);
            unsigned p3 = f2bf_rne(e[6]) | (f2bf_rne(e[7]) << 16);
            // logical slot gq (elems 8gq..8gq+7) at phys slot gq ^ (row&7)
            WsQ[row * 8 + (gq ^ (row & 7))] = make_uint4(p0, p1, p2, p3);
        }
        float s01 = add_nf(r8[0], r8[1]);
        float s23 = add_nf(r8[2], r8[3]);
        float s45 = add_nf(r8[4], r8[5]);
        float s67 = add_nf(r8[6], r8[7]);
        wn_s[row] = add_nf(add_nf(s01, s23), add_nf(s45, s67));  // np-exact
    }

    // a-frags: lane supplies A[m = lane&31][k = 16*kc + 8*g + j], bf16.
    int arow = wave * 32 + (lane & 31);
    const float* xrow = z_e + (size_t)(t0 + arow) * E_DIM;
    short8 afr[4];
#pragma unroll
    for (int kc = 0; kc < 4; ++kc) {
        int base = kc * 16 + g * 8;
        float4 a = *reinterpret_cast<const float4*>(xrow + base);
        float4 b = *reinterpret_cast<const float4*>(xrow + base + 4);
        afr[kc][0] = (short)f2bf_rne(a.x);
        afr[kc][1] = (short)f2bf_rne(a.y);
        afr[kc][2] = (short)f2bf_rne(a.z);
        afr[kc][3] = (short)f2bf_rne(a.w);
        afr[kc][4] = (short)f2bf_rne(b.x);
        afr[kc][5] = (short)f2bf_rne(b.y);
        afr[kc][6] = (short)f2bf_rne(b.z);
        afr[kc][7] = (short)f2bf_rne(b.w);
    }

    __syncthreads();  // Ws, wn_s, xn_s, key_s ready

    // ---- pass 1: quad-interleaved raw-acc max over 8 quads (32 tiles) ----
    float maxr[16];
#pragma unroll
    for (int r = 0; r < 16; ++r) maxr[r] = -INFINITY;

#pragma unroll 1
    for (int tq = 0; tq < 8; ++tq) {
        int c0 = tq * 128 + (lane & 31);   // quad's first tile column
        f32x16 A0, A1, A2, A3;
#pragma unroll
        for (int i = 0; i < 16; ++i) { A0[i] = 0.f; A1[i] = 0.f; A2[i] = 0.f; A3[i] = 0.f; }
#pragma unroll
        for (int kc = 0; kc < 4; ++kc) {
            int ps = (2 * kc + g) ^ (c0 & 7);  // identical across the quad
            const unsigned short* wsb = &Ws[c0 * E_DIM + ps * 8];
            short8 b0 = *reinterpret_cast<const short8*>(wsb);
            short8 b1 = *reinterpret_cast<const short8*>(wsb + 32 * E_DIM);
            short8 b2 = *reinterpret_cast<const short8*>(wsb + 64 * E_DIM);
            short8 b3 = *reinterpret_cast<const short8*>(wsb + 96 * E_DIM);
            A0 = __builtin_amdgcn_mfma_f32_32x32x16_bf16(afr[kc], b0, A0, 0, 0, 0);
            A1 = __builtin_amdgcn_mfma_f32_32x32x16_bf16(afr[kc], b1, A1, 0, 0, 0);
            A2 = __builtin_amdgcn_mfma_f32_32x32x16_bf16(afr[kc], b2, A2, 0, 0, 0);
            A3 = __builtin_amdgcn_mfma_f32_32x32x16_bf16(afr[kc], b3, A3, 0, 0, 0);
        }
#pragma unroll
        for (int r = 0; r < 16; ++r) {
            float m01 = fmaxf(A0[r], A1[r]);
            float m23 = fmaxf(A2[r], A3[r]);
            maxr[r] = fmaxf(maxr[r], fmaxf(m01, m23));
        }
    }

    // cross-column reduce (xor masks < 32 stay inside the lane>>5 group),
    // then fold the margin in-place: maxr becomes the enqueue threshold.
#pragma unroll
    for (int off = 1; off < 32; off <<= 1) {
#pragma unroll
        for (int r = 0; r < 16; ++r)
            maxr[r] = fmaxf(maxr[r], __shfl_xor(maxr[r], off, 64));
    }
#pragma unroll
    for (int r = 0; r < 16; ++r) maxr[r] -= HACC;

    // ---- pass 2: quad-interleaved enqueue of margin candidates ----
#pragma unroll 1
    for (int tq = 0; tq < 8; ++tq) {
        int c0 = tq * 128 + (lane & 31);
        f32x16 A0, A1, A2, A3;
#pragma unroll
        for (int i = 0; i < 16; ++i) { A0[i] = 0.f; A1[i] = 0.f; A2[i] = 0.f; A3[i] = 0.f; }
#pragma unroll
        for (int kc = 0; kc < 4; ++kc) {
            int ps = (2 * kc + g) ^ (c0 & 7);
            const unsigned short* wsb = &Ws[c0 * E_DIM + ps * 8];
            short8 b0 = *reinterpret_cast<const short8*>(wsb);
            short8 b1 = *reinterpret_cast<const short8*>(wsb + 32 * E_DIM);
            short8 b2 = *reinterpret_cast<const short8*>(wsb + 64 * E_DIM);
            short8 b3 = *reinterpret_cast<const short8*>(wsb + 96 * E_DIM);
            A0 = __builtin_amdgcn_mfma_f32_32x32x16_bf16(afr[kc], b0, A0, 0, 0, 0);
            A1 = __builtin_amdgcn_mfma_f32_32x32x16_bf16(afr[kc], b1, A1, 0, 0, 0);
            A2 = __builtin_amdgcn_mfma_f32_32x32x16_bf16(afr[kc], b2, A2, 0, 0, 0);
            A3 = __builtin_amdgcn_mfma_f32_32x32x16_bf16(afr[kc], b3, A3, 0, 0, 0);
        }
        float tmax = -INFINITY;
#pragma unroll
        for (int r = 0; r < 16; ++r) {
            float m01 = fmaxf(A0[r], A1[r]);
            float m23 = fmaxf(A2[r], A3[r]);
            tmax = fmaxf(tmax, fmaxf(m01, m23) - maxr[r]);
        }
        if (tmax >= 0.f) {  // rare: some code in this quad is within margin
#pragma unroll
            for (int r = 0; r < 16; ++r) {
                float av[4] = {A0[r], A1[r], A2[r], A3[r]};
#pragma unroll
                for (int t = 0; t < 4; ++t) {
                    if (av[t] >= maxr[r]) {
                        int row = (r & 3) + 8 * (r >> 2) + 4 * g;
                        int tl = wave * 32 + row;
                        int code = c0 + 32 * t;
                        int slot = atomicAdd(&qc_s, 1);
                        if (slot < QCAP)
                            q_s[slot] = ((unsigned)tl << 10) | (unsigned)code;
                        else  // overflow fallback: exact inline (correct, rare)
                            exact_key(t0, tl, code, wn_s[code], z_e, embed, xn_s, key_s);
                    }
                }
            }
        }
    }
    __syncthreads();

    // drain candidate queue with the exact fp32 chain
    int qn = qc_s;
    if (qn > QCAP) qn = QCAP;
    for (int e = tid; e < qn; e += 512) {
        unsigned q = q_s[e];
        int tl = (int)(q >> 10);
        int code = (int)(q & 1023u);
        exact_key(t0, tl, code, wn_s[code], z_e, embed, xn_s, key_s);
    }
    __syncthreads();

    // ---- fused epilogue (r3/r7/r10-verified): ind, z_q, diff, EMA scatter ----
    if (tid < TT) {
        int bi = (int)(unsigned)(key_s[tid] & 1023ull);
        bi_s[tid] = bi;
        out_ind[t0 + tid] = (float)bi;
    }
    __syncthreads();

    int rep = blockIdx.x & rep_mask;
    float* esum = esum_rep + (size_t)rep * (K_CODE * E_DIM);
    float* onehot = onehot_rep + (size_t)rep * K_CODE;

    float ds = 0.f;
#pragma unroll 4
    for (int it = 0; it < 32; ++it) {
        int tl = wave * 32 + it;                  // wave-uniform
        int bi = bi_s[tl];                        // broadcast
        float xv = z_e[(size_t)(t0 + tl) * E_DIM + lane];   // coalesced row
        float wv = embed[(size_t)bi * E_DIM + lane];        // coalesced row
        float rr = sub_nf(wv, xv);                          // np: r = fl(w-x)
        out_zq[(size_t)(t0 + tl) * E_DIM + lane] = add_nf(xv, rr);  // fl(x+r)
        ds = __builtin_fmaf(rr, rr, ds);
        atomicAdd(&esum[(size_t)bi * E_DIM + lane], xv);
        if (lane == 0) atomicAdd(&onehot[bi], 1.0f);
    }
#pragma unroll
    for (int o = 32; o > 0; o >>= 1) ds += __shfl_down(ds, o, 64);
    if (lane == 0) atomicAdd(diff_acc, ds);
}

// Fused finalize (r5/r6/r7/r9/r10 harness-verified): every block redundantly
// computes ncs[1024] + n with the same reduction tree as the verified
// finalize_cs; block 0 writes out_ncs/out_diff; each block updates its 16
// embed rows (identical mapping/arithmetic to the verified finalize_embed).
__global__ __launch_bounds__(256) void finalize_kernel(const float* __restrict__ cluster_size,
                                                       const float* __restrict__ onehot_rep,
                                                       const float* __restrict__ ws_diff,
                                                       const float* __restrict__ embed_avg,
                                                       const float* __restrict__ esum_rep,
                                                       float* __restrict__ out_diff,
                                                       float* __restrict__ out_ncs,
                                                       float* __restrict__ out_ne,
                                                       float* __restrict__ out_nea,
                                                       int nrep) {
    __shared__ float ncs_s[K_CODE];
    __shared__ float red[K_CODE];
    int tid = threadIdx.x;

#pragma unroll
    for (int i = 0; i < 4; ++i) {
        int k = tid + 256 * i;
        float oh = 0.f;
        for (int r = 0; r < nrep; ++r) oh += onehot_rep[(size_t)r * K_CODE + k];
        float ncs = DECAYF * cluster_size[k] + (1.0f - DECAYF) * oh;
        ncs_s[k] = ncs;
        red[k] = ncs;
    }
    __syncthreads();
    for (int s = 512; s > 0; s >>= 1) {
        for (int idx = tid; idx < s; idx += 256) red[idx] += red[idx + s];
        __syncthreads();
    }
    float n = red[0];

    if (blockIdx.x == 0) {
#pragma unroll
        for (int i = 0; i < 4; ++i) {
            int k = tid + 256 * i;
            out_ncs[k] = ncs_s[k];
        }
        if (tid == 0) out_diff[0] = ws_diff[0] * (1.0f / 4194304.0f);  // /2^22 exact
    }

    int k = blockIdx.x * 16 + (tid >> 4);  // row (same mapping as verified)
    int c = tid & 15;                      // float4 chunk
    float ncs = ncs_s[k];
    float cs = (ncs + EPSF) / (n + (float)K_CODE * EPSF) * n;

    size_t off = (size_t)k * E_DIM + (size_t)c * 4;
    float4 s4 = make_float4(0.f, 0.f, 0.f, 0.f);
    for (int r = 0; r < nrep; ++r) {
        float4 v = *reinterpret_cast<const float4*>(esum_rep + (size_t)r * (K_CODE * E_DIM) + off);
        s4.x += v.x; s4.y += v.y; s4.z += v.z; s4.w += v.w;
    }
    float4 a = *reinterpret_cast<const float4*>(embed_avg + off);
    float4 nea, ne;
    nea.x = DECAYF * a.x + (1.0f - DECAYF) * s4.x;
    nea.y = DECAYF * a.y + (1.0f - DECAYF) * s4.y;
    nea.z = DECAYF * a.z + (1.0f - DECAYF) * s4.z;
    nea.w = DECAYF * a.w + (1.0f - DECAYF) * s4.w;
    ne.x = nea.x / cs; ne.y = nea.y / cs; ne.z = nea.z / cs; ne.w = nea.w / cs;
    *reinterpret_cast<float4*>(out_nea + off) = nea;
    *reinterpret_cast<float4*>(out_ne + off) = ne;
}

extern "C" void kernel_launch(void* const* d_in, const int* in_sizes, int n_in,
                              void* d_out, int out_size, void* d_ws, size_t ws_size,
                              hipStream_t stream) {
    const float* z_e = (const float*)d_in[0];
    const float* embed = (const float*)d_in[1];
    const float* cluster_size = (const float*)d_in[2];
    const float* embed_avg = (const float*)d_in[3];

    float* out = (float*)d_out;
    float* o_zq = out;                   // 4194304
    float* o_diff = out + 4194304;       // 1
    float* o_ind = out + 4194305;        // 65536
    float* o_ne = out + 4194305 + 65536; // 65536
    float* o_ncs = o_ne + 65536;         // 1024
    float* o_nea = o_ncs + 1024;         // 65536

    float* ws = (float*)d_ws;
    float* ws_diff = ws + 0;
    float* ws_onehot = ws + 16;          // 8*1024

    int nrep = 1;
    while (nrep < 8 &&
           (size_t)(8208 + (size_t)(2 * nrep) * 65536) * sizeof(float) <= ws_size)
        nrep *= 2;

    float* ws_esum = ws + 8208;          // nrep*65536

    // one contiguous clear: diff, pad, onehot, esum
    hipMemsetAsync(ws, 0, (size_t)(8208 + (size_t)nrep * 65536) * sizeof(float), stream);

    dist_kernel<<<T_TOK / TT, 512, 0, stream>>>(z_e, embed, o_zq, o_ind, ws_diff,
                                                ws_esum, ws_onehot, nrep - 1);
    finalize_kernel<<<64, 256, 0, stream>>>(cluster_size, ws_onehot, ws_diff, embed_avg,
                                            ws_esum, o_diff, o_ncs, o_ne, o_nea, nrep);
}